// Round 1
// 791.438 us; speedup vs baseline: 1.2455x; 1.2455x over previous
//
#include <hip/hip_runtime.h>
#include <hip/hip_bf16.h>

#define D 256
#define G 512
#define PER 128
#define NROW (G*PER)   // 65536
#define LSEQ 1534
#define LP 1536
#define HID 512

typedef __hip_bfloat16 bf16;
typedef __attribute__((ext_vector_type(8))) short bf16x8;
typedef __attribute__((ext_vector_type(4))) float f32x4;

// ---------------------------------------------------------------------------
// K1: hats = relu(NEs @ Wa + ba)  (stored bf16), HAts = per-group max (f32)
// ---------------------------------------------------------------------------
__global__ __launch_bounds__(256) void k_hats(
    const float* __restrict__ NEs, const float* __restrict__ Wa,
    const float* __restrict__ ba, bf16* __restrict__ hats,
    float* __restrict__ HAts) {
  __shared__ __align__(16) float lds_a[32][D];   // 32 KB
  __shared__ float smax[4][D];                   // 4 KB
  const int tid = threadIdx.x;
  const int tx = tid & 63, ty = tid >> 6;
  const int g = blockIdx.x;
  float bav[4], colmax[4];
  #pragma unroll
  for (int j = 0; j < 4; ++j) { bav[j] = ba[tx + 64*j]; colmax[j] = 0.f; }

  for (int pass = 0; pass < 4; ++pass) {
    __syncthreads();
    const float4* src = (const float4*)(NEs + (size_t)(g*PER + pass*32) * D);
    float4* dst = (float4*)(&lds_a[0][0]);
    #pragma unroll
    for (int i = 0; i < 8; ++i) dst[i*256 + tid] = src[i*256 + tid];
    __syncthreads();

    float acc[8][4];
    #pragma unroll
    for (int i = 0; i < 8; ++i)
      #pragma unroll
      for (int j = 0; j < 4; ++j) acc[i][j] = 0.f;

    for (int k4 = 0; k4 < D/4; ++k4) {
      float4 av[8];
      #pragma unroll
      for (int i = 0; i < 8; ++i) av[i] = *(const float4*)&lds_a[ty*8 + i][k4*4];
      #pragma unroll
      for (int kk = 0; kk < 4; ++kk) {
        const float* wrow = Wa + (size_t)(k4*4 + kk) * D;
        float w[4];
        #pragma unroll
        for (int j = 0; j < 4; ++j) w[j] = wrow[tx + 64*j];
        #pragma unroll
        for (int i = 0; i < 8; ++i) {
          float a = ((const float*)&av[i])[kk];
          #pragma unroll
          for (int j = 0; j < 4; ++j) acc[i][j] = fmaf(a, w[j], acc[i][j]);
        }
      }
    }
    #pragma unroll
    for (int i = 0; i < 8; ++i) {
      size_t row = (size_t)(g*PER + pass*32 + ty*8 + i);
      #pragma unroll
      for (int j = 0; j < 4; ++j) {
        float h = acc[i][j] + bav[j];
        h = h > 0.f ? h : 0.f;
        colmax[j] = fmaxf(colmax[j], h);
        hats[row*D + tx + 64*j] = __float2bfloat16(h);
      }
    }
  }
  #pragma unroll
  for (int j = 0; j < 4; ++j) smax[ty][tx + 64*j] = colmax[j];
  __syncthreads();
  if (ty == 0) {
    #pragma unroll
    for (int j = 0; j < 4; ++j) {
      int c = tx + 64*j;
      HAts[g*D + c] = fmaxf(fmaxf(smax[0][c], smax[1][c]),
                            fmaxf(smax[2][c], smax[3][c]));
    }
  }
}

// ---------------------------------------------------------------------------
// K-wconv: Wp1 rows 768..1023 (fp32) -> MFMA-tiled bf16 layout WBt.
// ---------------------------------------------------------------------------
__global__ void k_wconv(const float* __restrict__ Wp1, bf16* __restrict__ WBt) {
  int id = blockIdx.x * 256 + threadIdx.x;   // id = k*512 + n
  int k = id >> 9, n = id & 511;
  float v = Wp1[(size_t)(768 + k) * HID + n];
  int dst = (n >> 7) * 32768
          + (((((n >> 4) & 7) * 8 + (k >> 5)) * 16 + (n & 15)) * 4 + ((k >> 3) & 3)) * 8
          + (k & 7);
  WBt[dst] = __float2bfloat16(v);
}

// ---------------------------------------------------------------------------
// K2: build x0 (C=256, L=1534) transposed sequence
// ---------------------------------------------------------------------------
__global__ void k_build_x0(const float* __restrict__ nodes,
                           const float* __restrict__ HAts,
                           const bf16* __restrict__ hats,
                           const int* __restrict__ act,
                           float* __restrict__ x0) {
  int t = blockIdx.x * 256 + threadIdx.x;
  int c = blockIdx.y;
  if (t >= LSEQ) return;
  float v;
  if (t == LSEQ - 1) {
    v = nodes[(size_t)(G-1)*D + c];
  } else {
    int r = t / 3, m = t - 3*r;
    if (m == 0)      v = nodes[(size_t)r*D + c];
    else if (m == 1) v = HAts[(size_t)r*D + c];
    else             v = __bfloat162float(hats[(size_t)(r*PER + act[r])*D + c]);
  }
  x0[(size_t)c*LP + t] = v;
}

// ---------------------------------------------------------------------------
// K-zero: clear split-K partial buffers (run first each launch)
// ---------------------------------------------------------------------------
__global__ __launch_bounds__(256) void k_zero(float4* __restrict__ p, int n4) {
  int i = blockIdx.x * 256 + threadIdx.x;
  const int stride = gridDim.x * 256;
  const float4 z = make_float4(0.f, 0.f, 0.f, 0.f);
  for (; i < n4; i += stride) p[i] = z;
}

// ---------------------------------------------------------------------------
// K3: TCN conv partial, split-K over cin-chunks of 32 (blockIdx.z).
// Block = 64t x 64ch, 256 threads, each thread 4t x 4ch.
// Accumulates conv (and Wd@x residual) into zeroed fp32 buffers via atomicAdd.
// x reads vectorized: tap windows rebuilt from 2-3 aligned ds_read_b128.
// ---------------------------------------------------------------------------
template<int DIL, int CPB, bool HASWD>
__global__ __launch_bounds__(256) void k_tcn3(
    const float* __restrict__ xin,
    const float* __restrict__ W,     // (Cout, Cin, 3)
    const float* __restrict__ Wd,    // (Cout, Cin) or unused
    float* __restrict__ ybuf,
    float* __restrict__ rbuf,
    int Cin) {
  __shared__ __align__(16) float xs[32][80];                         // 10.0 KB
  __shared__ __align__(16) float wst[3][32][68];                     // 25.5 KB
  __shared__ __align__(16) float wds[HASWD ? 32 : 1][HASWD ? 68 : 4];

  const int tid = threadIdx.x;
  const int tt = tid & 15;        // t-thread: t = t0 + tt*4 + it
  const int cc = tid >> 4;        // ch-thread: ch = o0 + cc*4 + ic
  const int t0 = blockIdx.x * 64;
  const int o0 = blockIdx.y * 64;

  float acc[4][4], res[4][4];
  #pragma unroll
  for (int it = 0; it < 4; ++it)
    #pragma unroll
    for (int ic = 0; ic < 4; ++ic) { acc[it][ic] = 0.f; res[it][ic] = 0.f; }

  for (int c = 0; c < CPB; ++c) {
    const int i0 = (blockIdx.z * CPB + c) * 32;
    __syncthreads();
    // stage x window: rows i0..i0+31, t' = t0-16 .. t0+63 (float4)
    for (int idx = tid; idx < 32*20; idx += 256) {
      int r = idx / 20, j4 = idx - r*20;
      int tp = t0 - 16 + j4*4;
      float4 v;
      if (tp >= 0) v = *(const float4*)&xin[(size_t)(i0 + r)*LP + tp];
      else         v = make_float4(0.f, 0.f, 0.f, 0.f);
      *(float4*)&xs[r][j4*4] = v;
    }
    // stage weights: wst[tap][i][o]
    for (int idx = tid; idx < 64*32; idx += 256) {
      int o = idx >> 5, i = idx & 31;
      const float* wp = &W[((size_t)(o0 + o)*Cin + i0 + i)*3];
      wst[0][i][o] = wp[0];
      wst[1][i][o] = wp[1];
      wst[2][i][o] = wp[2];
      if constexpr (HASWD) wds[i][o] = Wd[(size_t)(o0 + o)*Cin + i0 + i];
    }
    __syncthreads();

    const int base = 16 + tt*4;
    #pragma unroll 2
    for (int i = 0; i < 32; ++i) {
      float4 xv0, xv1, xv2;
      if constexpr (DIL == 1) {
        float4 A = *(const float4*)&xs[i][base - 4];
        float4 B = *(const float4*)&xs[i][base];
        xv0 = make_float4(A.z, A.w, B.x, B.y);
        xv1 = make_float4(A.w, B.x, B.y, B.z);
        xv2 = B;
      } else if constexpr (DIL == 2) {
        float4 A = *(const float4*)&xs[i][base - 4];
        float4 B = *(const float4*)&xs[i][base];
        xv0 = A;
        xv1 = make_float4(A.z, A.w, B.x, B.y);
        xv2 = B;
      } else {
        xv0 = *(const float4*)&xs[i][base - 2*DIL];
        xv1 = *(const float4*)&xs[i][base - DIL];
        xv2 = *(const float4*)&xs[i][base];
      }
      float4 w0 = *(const float4*)&wst[0][i][cc*4];
      float4 w1 = *(const float4*)&wst[1][i][cc*4];
      float4 w2 = *(const float4*)&wst[2][i][cc*4];
      #pragma unroll
      for (int it = 0; it < 4; ++it) {
        float x0 = ((const float*)&xv0)[it];
        float x1 = ((const float*)&xv1)[it];
        float x2 = ((const float*)&xv2)[it];
        #pragma unroll
        for (int ic = 0; ic < 4; ++ic) {
          float a = acc[it][ic];
          a = fmaf(x0, ((const float*)&w0)[ic], a);
          a = fmaf(x1, ((const float*)&w1)[ic], a);
          a = fmaf(x2, ((const float*)&w2)[ic], a);
          acc[it][ic] = a;
        }
      }
      if constexpr (HASWD) {
        float4 wd4 = *(const float4*)&wds[i][cc*4];
        #pragma unroll
        for (int it = 0; it < 4; ++it) {
          float x2 = ((const float*)&xv2)[it];
          #pragma unroll
          for (int ic = 0; ic < 4; ++ic)
            res[it][ic] = fmaf(x2, ((const float*)&wd4)[ic], res[it][ic]);
        }
      }
    }
  }

  // split-K epilogue: accumulate partials
  #pragma unroll
  for (int ic = 0; ic < 4; ++ic) {
    const int ch = o0 + cc*4 + ic;
    #pragma unroll
    for (int it = 0; it < 4; ++it) {
      const int t = t0 + tt*4 + it;
      if (t < LSEQ) {
        atomicAdd(&ybuf[(size_t)ch*LP + t], acc[it][ic]);
        if constexpr (HASWD) atomicAdd(&rbuf[(size_t)ch*LP + t], res[it][ic]);
      }
    }
  }
}

// ---------------------------------------------------------------------------
// K3b: TCN layer epilogue: out = relu(relu(conv+b) + res)
// ---------------------------------------------------------------------------
__global__ __launch_bounds__(256) void k_tcn_ep(
    const float* __restrict__ ybuf, const float* __restrict__ rbuf,
    const float* __restrict__ xin, const float* __restrict__ b,
    float* __restrict__ xout, int hasWd) {
  int t = blockIdx.x * 256 + threadIdx.x;
  int ch = blockIdx.y;
  if (t >= LSEQ) return;
  float y = ybuf[(size_t)ch*LP + t] + b[ch];
  y = y > 0.f ? y : 0.f;
  float r = hasWd ? rbuf[(size_t)ch*LP + t] : xin[(size_t)ch*LP + t];
  float v = y + r;
  xout[(size_t)ch*LP + t] = v > 0.f ? v : 0.f;
}

// ---------------------------------------------------------------------------
// K4: Gterm[g][j] = bp1[j] + sum_{m<768} [query|hs|HAts][g][m] * Wp1[m][j]
// ---------------------------------------------------------------------------
__global__ __launch_bounds__(256) void k_gterm(
    const float* __restrict__ query, const float* __restrict__ HAts,
    const float* __restrict__ xfin,
    const float* __restrict__ Wp1, const float* __restrict__ bp1,
    float* __restrict__ Gterm) {
  __shared__ __align__(16) float s[8][768];
  const int tid = threadIdx.x;
  const int g0 = blockIdx.x * 8;
  for (int gg = 0; gg < 8; ++gg) {
    int g = g0 + gg;
    s[gg][tid]       = query[(size_t)g*D + tid];
    s[gg][256 + tid] = xfin[(size_t)tid*LP + 3*g];
    s[gg][512 + tid] = HAts[(size_t)g*D + tid];
  }
  __syncthreads();
  float acc[8][2];
  #pragma unroll
  for (int gg = 0; gg < 8; ++gg) { acc[gg][0] = 0.f; acc[gg][1] = 0.f; }
  for (int m4 = 0; m4 < 768/4; ++m4) {
    float4 sv[8];
    #pragma unroll
    for (int gg = 0; gg < 8; ++gg) sv[gg] = *(const float4*)&s[gg][m4*4];
    #pragma unroll
    for (int kk = 0; kk < 4; ++kk) {
      int m = m4*4 + kk;
      float w0 = Wp1[(size_t)m*HID + tid];
      float w1 = Wp1[(size_t)m*HID + tid + 256];
      #pragma unroll
      for (int gg = 0; gg < 8; ++gg) {
        float a = ((const float*)&sv[gg])[kk];
        acc[gg][0] = fmaf(a, w0, acc[gg][0]);
        acc[gg][1] = fmaf(a, w1, acc[gg][1]);
      }
    }
  }
  float b0 = bp1[tid], b1 = bp1[tid + 256];
  for (int gg = 0; gg < 8; ++gg) {
    Gterm[(size_t)(g0+gg)*HID + tid]       = acc[gg][0] + b0;
    Gterm[(size_t)(g0+gg)*HID + tid + 256] = acc[gg][1] + b1;
  }
}

// ---------------------------------------------------------------------------
// K5: MFMA. out[i] = relu(hats[i,:]@Wp1b + Gterm[g,:]) @ Wp2 + bp2
// ---------------------------------------------------------------------------
__global__ __launch_bounds__(256) void k_final_mfma(
    const bf16* __restrict__ hats, const bf16* __restrict__ WBt,
    const float* __restrict__ Gterm, const float* __restrict__ Wp2,
    const float* __restrict__ bp2, float* __restrict__ out) {
  __shared__ __align__(16) unsigned short bs[32768];  // 64 KB
  __shared__ float gs[512];
  __shared__ float w2s[512];

  const int tid = threadIdx.x;
  const int wave = tid >> 6, lane = tid & 63;
  const int ln = lane & 15, quad = lane >> 4;
  const int row0 = blockIdx.x * 64;
  const int g = row0 >> 7;

  gs[tid]        = Gterm[(size_t)g*HID + tid];
  gs[tid + 256]  = Gterm[(size_t)g*HID + tid + 256];
  w2s[tid]       = Wp2[tid];
  w2s[tid + 256] = Wp2[tid + 256];

  bf16x8 afrag[8];
  {
    const uint4* ap = (const uint4*)(hats + (size_t)(row0 + wave*16 + ln) * D);
    #pragma unroll
    for (int kt = 0; kt < 8; ++kt) {
      uint4 t = ap[kt*4 + quad];
      afrag[kt] = *(const bf16x8*)&t;
    }
  }

  float osum[4] = {0.f, 0.f, 0.f, 0.f};

  for (int chunk = 0; chunk < 4; ++chunk) {
    __syncthreads();
    const uint4* src = (const uint4*)(WBt + (size_t)chunk * 32768);
    uint4* dst = (uint4*)bs;
    #pragma unroll
    for (int r = 0; r < 16; ++r) dst[r*256 + tid] = src[r*256 + tid];
    __syncthreads();

    #pragma unroll
    for (int nt = 0; nt < 8; ++nt) {
      f32x4 acc = {0.f, 0.f, 0.f, 0.f};
      #pragma unroll
      for (int kt = 0; kt < 8; ++kt) {
        const bf16x8 bfr = *(const bf16x8*)&bs[((nt*8 + kt)*64 + ln*4 + quad)*8];
        acc = __builtin_amdgcn_mfma_f32_16x16x32_bf16(afrag[kt], bfr, acc, 0, 0, 0);
      }
      int n = chunk*128 + nt*16 + ln;
      float gv = gs[n], wv = w2s[n];
      #pragma unroll
      for (int reg = 0; reg < 4; ++reg) {
        float h = acc[reg] + gv;
        h = h > 0.f ? h : 0.f;
        osum[reg] = fmaf(h, wv, osum[reg]);
      }
    }
  }

  #pragma unroll
  for (int reg = 0; reg < 4; ++reg) {
    float v = osum[reg];
    v += __shfl_xor(v, 1, 64);
    v += __shfl_xor(v, 2, 64);
    v += __shfl_xor(v, 4, 64);
    v += __shfl_xor(v, 8, 64);
    osum[reg] = v;
  }
  if (ln == 0) {
    float b2 = bp2[0];
    #pragma unroll
    for (int reg = 0; reg < 4; ++reg)
      out[row0 + wave*16 + quad*4 + reg] = osum[reg] + b2;
  }
}

// ---------------------------------------------------------------------------
extern "C" void kernel_launch(void* const* d_in, const int* in_sizes, int n_in,
                              void* d_out, int out_size, void* d_ws, size_t ws_size,
                              hipStream_t stream) {
  (void)in_sizes; (void)n_in; (void)out_size; (void)ws_size;
  const float* NEs   = (const float*)d_in[0];
  const float* nodes = (const float*)d_in[1];
  const float* query = (const float*)d_in[2];
  const int*   act   = (const int*)d_in[4];
  const float* Wa    = (const float*)d_in[5];
  const float* ba    = (const float*)d_in[6];
  const float* Wc0   = (const float*)d_in[7];
  const float* bc0   = (const float*)d_in[8];
  const float* Wc1   = (const float*)d_in[9];
  const float* bc1   = (const float*)d_in[10];
  const float* Wd1   = (const float*)d_in[11];
  const float* Wc2   = (const float*)d_in[12];
  const float* bc2   = (const float*)d_in[13];
  const float* Wc3   = (const float*)d_in[14];
  const float* bc3   = (const float*)d_in[15];
  const float* Wd3   = (const float*)d_in[16];
  const float* Wp1   = (const float*)d_in[17];
  const float* bp1   = (const float*)d_in[18];
  const float* Wp2   = (const float*)d_in[19];
  const float* bp2   = (const float*)d_in[20];
  float* out = (float*)d_out;

  char* ws = (char*)d_ws;
  bf16*  hats  = (bf16*)ws;  ws += (size_t)NROW * D * sizeof(bf16);
  float* HAts  = (float*)ws; ws += (size_t)G * D * sizeof(float);
  float* xa    = (float*)ws; ws += (size_t)512 * LP * sizeof(float);
  float* xb    = (float*)ws; ws += (size_t)512 * LP * sizeof(float);
  float* Gterm = (float*)ws; ws += (size_t)G * HID * sizeof(float);
  bf16*  WBt   = (bf16*)ws;  ws += (size_t)D * HID * sizeof(bf16);
  // split-K partial buffers (zeroed each launch): 2304 rows x LP
  float* yb0 = (float*)ws; ws += (size_t)256 * LP * sizeof(float);
  float* yb1 = (float*)ws; ws += (size_t)512 * LP * sizeof(float);
  float* rb1 = (float*)ws; ws += (size_t)512 * LP * sizeof(float);
  float* yb2 = (float*)ws; ws += (size_t)512 * LP * sizeof(float);
  float* yb3 = (float*)ws; ws += (size_t)256 * LP * sizeof(float);
  float* rb3 = (float*)ws; ws += (size_t)256 * LP * sizeof(float);

  k_zero<<<1024, 256, 0, stream>>>((float4*)yb0, (2304 * LP) / 4);
  k_hats<<<G, 256, 0, stream>>>(NEs, Wa, ba, hats, HAts);
  k_wconv<<<512, 256, 0, stream>>>(Wp1, WBt);
  k_build_x0<<<dim3(6, 256), 256, 0, stream>>>(nodes, HAts, hats, act, xa);

  k_tcn3<1, 1, false><<<dim3(24, 4, 8), 256, 0, stream>>>(xa, Wc0, nullptr, yb0, nullptr, 256);
  k_tcn_ep<<<dim3(6, 256), 256, 0, stream>>>(yb0, nullptr, xa, bc0, xb, 0);
  k_tcn3<2, 1, true ><<<dim3(24, 8, 8), 256, 0, stream>>>(xb, Wc1, Wd1,    yb1, rb1,     256);
  k_tcn_ep<<<dim3(6, 512), 256, 0, stream>>>(yb1, rb1, xb, bc1, xa, 1);
  k_tcn3<4, 2, false><<<dim3(24, 8, 8), 256, 0, stream>>>(xa, Wc2, nullptr, yb2, nullptr, 512);
  k_tcn_ep<<<dim3(6, 512), 256, 0, stream>>>(yb2, nullptr, xa, bc2, xb, 0);
  k_tcn3<8, 2, true ><<<dim3(24, 4, 8), 256, 0, stream>>>(xb, Wc3, Wd3,    yb3, rb3,     512);
  k_tcn_ep<<<dim3(6, 256), 256, 0, stream>>>(yb3, rb3, xb, bc3, xa, 1);

  k_gterm<<<G/8, 256, 0, stream>>>(query, HAts, xa, Wp1, bp1, Gterm);
  k_final_mfma<<<NROW/64, 256, 0, stream>>>(hats, WBt, Gterm, Wp2, bp2, out);
}

// Round 2
// 513.472 us; speedup vs baseline: 1.9198x; 1.5413x over previous
//
#include <hip/hip_runtime.h>
#include <hip/hip_bf16.h>

#define D 256
#define G 512
#define PER 128
#define NROW (G*PER)   // 65536
#define LSEQ 1534
#define LP 1536
#define HID 512

typedef __hip_bfloat16 bf16;
typedef __attribute__((ext_vector_type(8))) short bf16x8;
typedef __attribute__((ext_vector_type(4))) float f32x4;

// ---------------------------------------------------------------------------
// K1: hats = relu(NEs @ Wa + ba)  (stored bf16), HAts = per-group max (f32)
// ---------------------------------------------------------------------------
__global__ __launch_bounds__(256) void k_hats(
    const float* __restrict__ NEs, const float* __restrict__ Wa,
    const float* __restrict__ ba, bf16* __restrict__ hats,
    float* __restrict__ HAts) {
  __shared__ __align__(16) float lds_a[32][D];   // 32 KB
  __shared__ float smax[4][D];                   // 4 KB
  const int tid = threadIdx.x;
  const int tx = tid & 63, ty = tid >> 6;
  const int g = blockIdx.x;
  float bav[4], colmax[4];
  #pragma unroll
  for (int j = 0; j < 4; ++j) { bav[j] = ba[tx + 64*j]; colmax[j] = 0.f; }

  for (int pass = 0; pass < 4; ++pass) {
    __syncthreads();
    const float4* src = (const float4*)(NEs + (size_t)(g*PER + pass*32) * D);
    float4* dst = (float4*)(&lds_a[0][0]);
    #pragma unroll
    for (int i = 0; i < 8; ++i) dst[i*256 + tid] = src[i*256 + tid];
    __syncthreads();

    float acc[8][4];
    #pragma unroll
    for (int i = 0; i < 8; ++i)
      #pragma unroll
      for (int j = 0; j < 4; ++j) acc[i][j] = 0.f;

    for (int k4 = 0; k4 < D/4; ++k4) {
      float4 av[8];
      #pragma unroll
      for (int i = 0; i < 8; ++i) av[i] = *(const float4*)&lds_a[ty*8 + i][k4*4];
      #pragma unroll
      for (int kk = 0; kk < 4; ++kk) {
        const float* wrow = Wa + (size_t)(k4*4 + kk) * D;
        float w[4];
        #pragma unroll
        for (int j = 0; j < 4; ++j) w[j] = wrow[tx + 64*j];
        #pragma unroll
        for (int i = 0; i < 8; ++i) {
          float a = ((const float*)&av[i])[kk];
          #pragma unroll
          for (int j = 0; j < 4; ++j) acc[i][j] = fmaf(a, w[j], acc[i][j]);
        }
      }
    }
    #pragma unroll
    for (int i = 0; i < 8; ++i) {
      size_t row = (size_t)(g*PER + pass*32 + ty*8 + i);
      #pragma unroll
      for (int j = 0; j < 4; ++j) {
        float h = acc[i][j] + bav[j];
        h = h > 0.f ? h : 0.f;
        colmax[j] = fmaxf(colmax[j], h);
        hats[row*D + tx + 64*j] = __float2bfloat16(h);
      }
    }
  }
  #pragma unroll
  for (int j = 0; j < 4; ++j) smax[ty][tx + 64*j] = colmax[j];
  __syncthreads();
  if (ty == 0) {
    #pragma unroll
    for (int j = 0; j < 4; ++j) {
      int c = tx + 64*j;
      HAts[g*D + c] = fmaxf(fmaxf(smax[0][c], smax[1][c]),
                            fmaxf(smax[2][c], smax[3][c]));
    }
  }
}

// ---------------------------------------------------------------------------
// K-wconv: Wp1 rows 768..1023 (fp32) -> MFMA-tiled bf16 layout WBt.
// ---------------------------------------------------------------------------
__global__ void k_wconv(const float* __restrict__ Wp1, bf16* __restrict__ WBt) {
  int id = blockIdx.x * 256 + threadIdx.x;   // id = k*512 + n
  int k = id >> 9, n = id & 511;
  float v = Wp1[(size_t)(768 + k) * HID + n];
  int dst = (n >> 7) * 32768
          + (((((n >> 4) & 7) * 8 + (k >> 5)) * 16 + (n & 15)) * 4 + ((k >> 3) & 3)) * 8
          + (k & 7);
  WBt[dst] = __float2bfloat16(v);
}

// ---------------------------------------------------------------------------
// K2: build x0 (C=256, L=1534) transposed sequence
// ---------------------------------------------------------------------------
__global__ void k_build_x0(const float* __restrict__ nodes,
                           const float* __restrict__ HAts,
                           const bf16* __restrict__ hats,
                           const int* __restrict__ act,
                           float* __restrict__ x0) {
  int t = blockIdx.x * 256 + threadIdx.x;
  int c = blockIdx.y;
  if (t >= LSEQ) return;
  float v;
  if (t == LSEQ - 1) {
    v = nodes[(size_t)(G-1)*D + c];
  } else {
    int r = t / 3, m = t - 3*r;
    if (m == 0)      v = nodes[(size_t)r*D + c];
    else if (m == 1) v = HAts[(size_t)r*D + c];
    else             v = __bfloat162float(hats[(size_t)(r*PER + act[r])*D + c]);
  }
  x0[(size_t)c*LP + t] = v;
}

// ---------------------------------------------------------------------------
// K3: TCN conv partials, split-K over cin (blockIdx.z owns CPB chunks of 32).
// Block = 64t x 64ch, 256 threads, each thread 4t x 4ch.
// NO atomics: each z-slice writes its own [Cout][LP] partial (coalesced f4).
// ---------------------------------------------------------------------------
template<int DIL, int CPB, bool HASWD>
__global__ __launch_bounds__(256) void k_tcn4(
    const float* __restrict__ xin,
    const float* __restrict__ W,     // (Cout, Cin, 3)
    const float* __restrict__ Wd,    // (Cout, Cin) or unused
    float* __restrict__ ybuf,        // [NZ][Cout][LP]
    float* __restrict__ rbuf,        // [NZ][Cout][LP] (HASWD only)
    int Cin) {
  __shared__ __align__(16) float xs[32][80];                         // 10.0 KB
  __shared__ __align__(16) float wst[3][32][68];                     // 25.5 KB
  __shared__ __align__(16) float wds[HASWD ? 32 : 1][HASWD ? 68 : 4];

  const int tid = threadIdx.x;
  const int tt = tid & 15;        // t-thread: t = t0 + tt*4 + it
  const int cc = tid >> 4;        // ch-thread: ch = o0 + cc*4 + ic
  const int t0 = blockIdx.x * 64;
  const int o0 = blockIdx.y * 64;
  const int Cout = gridDim.y << 6;

  float acc[4][4], res[4][4];
  #pragma unroll
  for (int it = 0; it < 4; ++it)
    #pragma unroll
    for (int ic = 0; ic < 4; ++ic) { acc[it][ic] = 0.f; res[it][ic] = 0.f; }

  for (int c = 0; c < CPB; ++c) {
    const int i0 = (blockIdx.z * CPB + c) * 32;
    __syncthreads();
    // stage x window: rows i0..i0+31, t' = t0-16 .. t0+63 (float4)
    for (int idx = tid; idx < 32*20; idx += 256) {
      int r = idx / 20, j4 = idx - r*20;
      int tp = t0 - 16 + j4*4;
      float4 v;
      if (tp >= 0) v = *(const float4*)&xin[(size_t)(i0 + r)*LP + tp];
      else         v = make_float4(0.f, 0.f, 0.f, 0.f);
      *(float4*)&xs[r][j4*4] = v;
    }
    // stage weights: wst[tap][i][o]
    for (int idx = tid; idx < 64*32; idx += 256) {
      int o = idx >> 5, i = idx & 31;
      const float* wp = &W[((size_t)(o0 + o)*Cin + i0 + i)*3];
      wst[0][i][o] = wp[0];
      wst[1][i][o] = wp[1];
      wst[2][i][o] = wp[2];
      if constexpr (HASWD) wds[i][o] = Wd[(size_t)(o0 + o)*Cin + i0 + i];
    }
    __syncthreads();

    const int base = 16 + tt*4;
    #pragma unroll 2
    for (int i = 0; i < 32; ++i) {
      float4 xv0, xv1, xv2;
      if constexpr (DIL == 1) {
        float4 A = *(const float4*)&xs[i][base - 4];
        float4 B = *(const float4*)&xs[i][base];
        xv0 = make_float4(A.z, A.w, B.x, B.y);
        xv1 = make_float4(A.w, B.x, B.y, B.z);
        xv2 = B;
      } else if constexpr (DIL == 2) {
        float4 A = *(const float4*)&xs[i][base - 4];
        float4 B = *(const float4*)&xs[i][base];
        xv0 = A;
        xv1 = make_float4(A.z, A.w, B.x, B.y);
        xv2 = B;
      } else {
        xv0 = *(const float4*)&xs[i][base - 2*DIL];
        xv1 = *(const float4*)&xs[i][base - DIL];
        xv2 = *(const float4*)&xs[i][base];
      }
      float4 w0 = *(const float4*)&wst[0][i][cc*4];
      float4 w1 = *(const float4*)&wst[1][i][cc*4];
      float4 w2 = *(const float4*)&wst[2][i][cc*4];
      #pragma unroll
      for (int it = 0; it < 4; ++it) {
        float x0 = ((const float*)&xv0)[it];
        float x1 = ((const float*)&xv1)[it];
        float x2 = ((const float*)&xv2)[it];
        #pragma unroll
        for (int ic = 0; ic < 4; ++ic) {
          float a = acc[it][ic];
          a = fmaf(x0, ((const float*)&w0)[ic], a);
          a = fmaf(x1, ((const float*)&w1)[ic], a);
          a = fmaf(x2, ((const float*)&w2)[ic], a);
          acc[it][ic] = a;
        }
      }
      if constexpr (HASWD) {
        float4 wd4 = *(const float4*)&wds[i][cc*4];
        #pragma unroll
        for (int it = 0; it < 4; ++it) {
          float x2 = ((const float*)&xv2)[it];
          #pragma unroll
          for (int ic = 0; ic < 4; ++ic)
            res[it][ic] = fmaf(x2, ((const float*)&wd4)[ic], res[it][ic]);
        }
      }
    }
  }

  // write partials (coalesced float4; t=1534/1535 are padding, never read)
  const int t = t0 + tt*4;
  #pragma unroll
  for (int ic = 0; ic < 4; ++ic) {
    const int ch = o0 + cc*4 + ic;
    const size_t off = ((size_t)blockIdx.z * Cout + ch) * LP + t;
    float4 v = make_float4(acc[0][ic], acc[1][ic], acc[2][ic], acc[3][ic]);
    *(float4*)&ybuf[off] = v;
    if constexpr (HASWD) {
      float4 rv = make_float4(res[0][ic], res[1][ic], res[2][ic], res[3][ic]);
      *(float4*)&rbuf[off] = rv;
    }
  }
}

// ---------------------------------------------------------------------------
// K3b: reduce NZ partial slices: out = relu(relu(sum_y+b) + res)
// grid = (Cout), 384 threads, one float4 of t per thread.
// ---------------------------------------------------------------------------
template<int NZ, bool HASWD>
__global__ __launch_bounds__(384) void k_tcn_red(
    const float* __restrict__ ybuf, const float* __restrict__ rbuf,
    const float* __restrict__ xin, const float* __restrict__ b,
    float* __restrict__ xout) {
  const int ch = blockIdx.x;
  const int Cout = gridDim.x;
  const int t = threadIdx.x * 4;
  const size_t stride = (size_t)Cout * LP;
  const size_t base = (size_t)ch * LP + t;

  float4 y = *(const float4*)&ybuf[base];
  #pragma unroll
  for (int z = 1; z < NZ; ++z) {
    float4 u = *(const float4*)&ybuf[base + z*stride];
    y.x += u.x; y.y += u.y; y.z += u.z; y.w += u.w;
  }
  const float bv = b[ch];
  y.x = fmaxf(y.x + bv, 0.f); y.y = fmaxf(y.y + bv, 0.f);
  y.z = fmaxf(y.z + bv, 0.f); y.w = fmaxf(y.w + bv, 0.f);

  float4 r;
  if constexpr (HASWD) {
    r = *(const float4*)&rbuf[base];
    #pragma unroll
    for (int z = 1; z < NZ; ++z) {
      float4 u = *(const float4*)&rbuf[base + z*stride];
      r.x += u.x; r.y += u.y; r.z += u.z; r.w += u.w;
    }
  } else {
    r = *(const float4*)&xin[base];
  }
  float4 v;
  v.x = fmaxf(y.x + r.x, 0.f); v.y = fmaxf(y.y + r.y, 0.f);
  v.z = fmaxf(y.z + r.z, 0.f); v.w = fmaxf(y.w + r.w, 0.f);
  *(float4*)&xout[base] = v;
}

// ---------------------------------------------------------------------------
// K4: Gterm[g][j] = bp1[j] + sum_{m<768} [query|hs|HAts][g][m] * Wp1[m][j]
// ---------------------------------------------------------------------------
__global__ __launch_bounds__(256) void k_gterm(
    const float* __restrict__ query, const float* __restrict__ HAts,
    const float* __restrict__ xfin,
    const float* __restrict__ Wp1, const float* __restrict__ bp1,
    float* __restrict__ Gterm) {
  __shared__ __align__(16) float s[8][768];
  const int tid = threadIdx.x;
  const int g0 = blockIdx.x * 8;
  for (int gg = 0; gg < 8; ++gg) {
    int g = g0 + gg;
    s[gg][tid]       = query[(size_t)g*D + tid];
    s[gg][256 + tid] = xfin[(size_t)tid*LP + 3*g];
    s[gg][512 + tid] = HAts[(size_t)g*D + tid];
  }
  __syncthreads();
  float acc[8][2];
  #pragma unroll
  for (int gg = 0; gg < 8; ++gg) { acc[gg][0] = 0.f; acc[gg][1] = 0.f; }
  for (int m4 = 0; m4 < 768/4; ++m4) {
    float4 sv[8];
    #pragma unroll
    for (int gg = 0; gg < 8; ++gg) sv[gg] = *(const float4*)&s[gg][m4*4];
    #pragma unroll
    for (int kk = 0; kk < 4; ++kk) {
      int m = m4*4 + kk;
      float w0 = Wp1[(size_t)m*HID + tid];
      float w1 = Wp1[(size_t)m*HID + tid + 256];
      #pragma unroll
      for (int gg = 0; gg < 8; ++gg) {
        float a = ((const float*)&sv[gg])[kk];
        acc[gg][0] = fmaf(a, w0, acc[gg][0]);
        acc[gg][1] = fmaf(a, w1, acc[gg][1]);
      }
    }
  }
  float b0 = bp1[tid], b1 = bp1[tid + 256];
  for (int gg = 0; gg < 8; ++gg) {
    Gterm[(size_t)(g0+gg)*HID + tid]       = acc[gg][0] + b0;
    Gterm[(size_t)(g0+gg)*HID + tid + 256] = acc[gg][1] + b1;
  }
}

// ---------------------------------------------------------------------------
// K5: MFMA. out[i] = relu(hats[i,:]@Wp1b + Gterm[g,:]) @ Wp2 + bp2
// ---------------------------------------------------------------------------
__global__ __launch_bounds__(256) void k_final_mfma(
    const bf16* __restrict__ hats, const bf16* __restrict__ WBt,
    const float* __restrict__ Gterm, const float* __restrict__ Wp2,
    const float* __restrict__ bp2, float* __restrict__ out) {
  __shared__ __align__(16) unsigned short bs[32768];  // 64 KB
  __shared__ float gs[512];
  __shared__ float w2s[512];

  const int tid = threadIdx.x;
  const int wave = tid >> 6, lane = tid & 63;
  const int ln = lane & 15, quad = lane >> 4;
  const int row0 = blockIdx.x * 64;
  const int g = row0 >> 7;

  gs[tid]        = Gterm[(size_t)g*HID + tid];
  gs[tid + 256]  = Gterm[(size_t)g*HID + tid + 256];
  w2s[tid]       = Wp2[tid];
  w2s[tid + 256] = Wp2[tid + 256];

  bf16x8 afrag[8];
  {
    const uint4* ap = (const uint4*)(hats + (size_t)(row0 + wave*16 + ln) * D);
    #pragma unroll
    for (int kt = 0; kt < 8; ++kt) {
      uint4 t = ap[kt*4 + quad];
      afrag[kt] = *(const bf16x8*)&t;
    }
  }

  float osum[4] = {0.f, 0.f, 0.f, 0.f};

  for (int chunk = 0; chunk < 4; ++chunk) {
    __syncthreads();
    const uint4* src = (const uint4*)(WBt + (size_t)chunk * 32768);
    uint4* dst = (uint4*)bs;
    #pragma unroll
    for (int r = 0; r < 16; ++r) dst[r*256 + tid] = src[r*256 + tid];
    __syncthreads();

    #pragma unroll
    for (int nt = 0; nt < 8; ++nt) {
      f32x4 acc = {0.f, 0.f, 0.f, 0.f};
      #pragma unroll
      for (int kt = 0; kt < 8; ++kt) {
        const bf16x8 bfr = *(const bf16x8*)&bs[((nt*8 + kt)*64 + ln*4 + quad)*8];
        acc = __builtin_amdgcn_mfma_f32_16x16x32_bf16(afrag[kt], bfr, acc, 0, 0, 0);
      }
      int n = chunk*128 + nt*16 + ln;
      float gv = gs[n], wv = w2s[n];
      #pragma unroll
      for (int reg = 0; reg < 4; ++reg) {
        float h = acc[reg] + gv;
        h = h > 0.f ? h : 0.f;
        osum[reg] = fmaf(h, wv, osum[reg]);
      }
    }
  }

  #pragma unroll
  for (int reg = 0; reg < 4; ++reg) {
    float v = osum[reg];
    v += __shfl_xor(v, 1, 64);
    v += __shfl_xor(v, 2, 64);
    v += __shfl_xor(v, 4, 64);
    v += __shfl_xor(v, 8, 64);
    osum[reg] = v;
  }
  if (ln == 0) {
    float b2 = bp2[0];
    #pragma unroll
    for (int reg = 0; reg < 4; ++reg)
      out[row0 + wave*16 + quad*4 + reg] = osum[reg] + b2;
  }
}

// ---------------------------------------------------------------------------
extern "C" void kernel_launch(void* const* d_in, const int* in_sizes, int n_in,
                              void* d_out, int out_size, void* d_ws, size_t ws_size,
                              hipStream_t stream) {
  (void)in_sizes; (void)n_in; (void)out_size; (void)ws_size;
  const float* NEs   = (const float*)d_in[0];
  const float* nodes = (const float*)d_in[1];
  const float* query = (const float*)d_in[2];
  const int*   act   = (const int*)d_in[4];
  const float* Wa    = (const float*)d_in[5];
  const float* ba    = (const float*)d_in[6];
  const float* Wc0   = (const float*)d_in[7];
  const float* bc0   = (const float*)d_in[8];
  const float* Wc1   = (const float*)d_in[9];
  const float* bc1   = (const float*)d_in[10];
  const float* Wd1   = (const float*)d_in[11];
  const float* Wc2   = (const float*)d_in[12];
  const float* bc2   = (const float*)d_in[13];
  const float* Wc3   = (const float*)d_in[14];
  const float* bc3   = (const float*)d_in[15];
  const float* Wd3   = (const float*)d_in[16];
  const float* Wp1   = (const float*)d_in[17];
  const float* bp1   = (const float*)d_in[18];
  const float* Wp2   = (const float*)d_in[19];
  const float* bp2   = (const float*)d_in[20];
  float* out = (float*)d_out;

  char* ws = (char*)d_ws;
  bf16*  hats  = (bf16*)ws;  ws += (size_t)NROW * D * sizeof(bf16);
  float* HAts  = (float*)ws; ws += (size_t)G * D * sizeof(float);
  float* xa    = (float*)ws; ws += (size_t)512 * LP * sizeof(float);
  float* xb    = (float*)ws; ws += (size_t)512 * LP * sizeof(float);
  float* Gterm = (float*)ws; ws += (size_t)G * HID * sizeof(float);
  bf16*  WBt   = (bf16*)ws;  ws += (size_t)D * HID * sizeof(bf16);
  // split-K partial buffers: up to 2048 rows x LP each (12.6 MB each)
  float* P0 = (float*)ws; ws += (size_t)2048 * LP * sizeof(float);
  float* P1 = (float*)ws; ws += (size_t)2048 * LP * sizeof(float);

  k_hats<<<G, 256, 0, stream>>>(NEs, Wa, ba, hats, HAts);
  k_wconv<<<512, 256, 0, stream>>>(Wp1, WBt);
  k_build_x0<<<dim3(6, 256), 256, 0, stream>>>(nodes, HAts, hats, act, xa);

  // L0: 256->256, dil=1, NZ=8 (CPB=1): 24*4*8 = 768 blocks
  k_tcn4<1, 1, false><<<dim3(24, 4, 8), 256, 0, stream>>>(xa, Wc0, nullptr, P0, nullptr, 256);
  k_tcn_red<8, false><<<256, 384, 0, stream>>>(P0, nullptr, xa, bc0, xb);
  // L1: 256->512, dil=2, Wd, NZ=4 (CPB=2): 24*8*4 = 768 blocks
  k_tcn4<2, 2, true ><<<dim3(24, 8, 4), 256, 0, stream>>>(xb, Wc1, Wd1, P0, P1, 256);
  k_tcn_red<4, true ><<<512, 384, 0, stream>>>(P0, P1, xb, bc1, xa);
  // L2: 512->512, dil=4, NZ=4 (CPB=4): 24*8*4 = 768 blocks
  k_tcn4<4, 4, false><<<dim3(24, 8, 4), 256, 0, stream>>>(xa, Wc2, nullptr, P0, nullptr, 512);
  k_tcn_red<4, false><<<512, 384, 0, stream>>>(P0, nullptr, xa, bc2, xb);
  // L3: 512->256, dil=8, Wd, NZ=8 (CPB=2): 24*4*8 = 768 blocks
  k_tcn4<8, 2, true ><<<dim3(24, 4, 8), 256, 0, stream>>>(xb, Wc3, Wd3, P0, P1, 512);
  k_tcn_red<8, true ><<<256, 384, 0, stream>>>(P0, P1, xb, bc3, xa);

  k_gterm<<<G/8, 256, 0, stream>>>(query, HAts, xa, Wp1, bp1, Gterm);
  k_final_mfma<<<NROW/64, 256, 0, stream>>>(hats, WBt, Gterm, Wp2, bp2, out);
}

// Round 3
// 440.327 us; speedup vs baseline: 2.2387x; 1.1661x over previous
//
#include <hip/hip_runtime.h>
#include <hip/hip_bf16.h>

#define D 256
#define G 512
#define PER 128
#define NROW (G*PER)   // 65536
#define LSEQ 1534
#define LP 1536
#define HID 512

typedef __hip_bfloat16 bf16;
typedef __attribute__((ext_vector_type(8))) short bf16x8;
typedef __attribute__((ext_vector_type(4))) float f32x4;

// ---------------------------------------------------------------------------
// K-zeroH: zero HAts (needed for uint atomicMax accumulation)
// ---------------------------------------------------------------------------
__global__ __launch_bounds__(256) void k_zeroH(float4* __restrict__ p) {
  p[blockIdx.x * 256 + threadIdx.x] = make_float4(0.f, 0.f, 0.f, 0.f);
}

// ---------------------------------------------------------------------------
// K-waprep: Wa (256x256 fp32, [k][n]) -> MFMA-tiled bf16 hi/lo buffers.
// Same tiling as k_wconv (2 chunks of 128 cols).
// ---------------------------------------------------------------------------
__global__ void k_waprep(const float* __restrict__ Wa,
                         bf16* __restrict__ WAhi, bf16* __restrict__ WAlo) {
  int id = blockIdx.x * 256 + threadIdx.x;   // id = k*256 + n
  int k = id >> 8, n = id & 255;
  float v = Wa[(size_t)k * D + n];
  bf16 h = __float2bfloat16(v);
  float hf = __bfloat162float(h);
  bf16 l = __float2bfloat16(v - hf);
  int dst = (n >> 7) * 32768
          + (((((n >> 4) & 7) * 8 + (k >> 5)) * 16 + (n & 15)) * 4 + ((k >> 3) & 3)) * 8
          + (k & 7);
  WAhi[dst] = h;
  WAlo[dst] = l;
}

// ---------------------------------------------------------------------------
// K1: hats = relu(NEs @ Wa + ba) via split-bf16 MFMA (AhiBhi+AloBhi+AhiBlo).
// 64 rows/block, 4 waves; B staged 64KB/chunk; LDS-bounce coalesced stores;
// HAts via quad-shuffle colmax + uint atomicMax (values >= 0, HAts zeroed).
// ---------------------------------------------------------------------------
__global__ __launch_bounds__(256) void k_hats_mfma(
    const float* __restrict__ NEs, const bf16* __restrict__ WAhi,
    const bf16* __restrict__ WAlo, const float* __restrict__ ba,
    bf16* __restrict__ hats, float* __restrict__ HAts) {
  __shared__ __align__(16) unsigned short bs[32768];  // 64 KB (reused as bounce)
  __shared__ float wsmax[4][128];

  const int tid = threadIdx.x;
  const int wave = tid >> 6, lane = tid & 63;
  const int ln = lane & 15, quad = lane >> 4;
  const int row0 = blockIdx.x * 64;
  const int g = row0 >> 7;

  // A fragments: hi/lo bf16 split of this lane's NEs row slices
  bf16x8 afH[8], afL[8];
  {
    const float4* ap = (const float4*)(NEs + (size_t)(row0 + wave*16 + ln) * D);
    #pragma unroll
    for (int kt = 0; kt < 8; ++kt) {
      float4 x0 = ap[kt*8 + quad*2];
      float4 x1 = ap[kt*8 + quad*2 + 1];
      float xv[8] = {x0.x, x0.y, x0.z, x0.w, x1.x, x1.y, x1.z, x1.w};
      bf16x8 hv, lv;
      #pragma unroll
      for (int e = 0; e < 8; ++e) {
        bf16 h = __float2bfloat16(xv[e]);
        bf16 l = __float2bfloat16(xv[e] - __bfloat162float(h));
        hv[e] = *(short*)&h;
        lv[e] = *(short*)&l;
      }
      afH[kt] = hv;
      afL[kt] = lv;
    }
  }

  float* bsf = (float*)bs;   // bounce view: [64][140] floats (35 KB)

  for (int chunk = 0; chunk < 2; ++chunk) {
    f32x4 acc[8];
    #pragma unroll
    for (int nt = 0; nt < 8; ++nt) acc[nt] = (f32x4){0.f, 0.f, 0.f, 0.f};

    // ---- hi weights: acc += Ahi@Bhi + Alo@Bhi ----
    __syncthreads();
    {
      const uint4* src = (const uint4*)(WAhi + (size_t)chunk * 32768);
      uint4* dst = (uint4*)bs;
      #pragma unroll
      for (int r = 0; r < 16; ++r) dst[r*256 + tid] = src[r*256 + tid];
    }
    __syncthreads();
    #pragma unroll
    for (int nt = 0; nt < 8; ++nt)
      #pragma unroll
      for (int kt = 0; kt < 8; ++kt) {
        const bf16x8 bfr = *(const bf16x8*)&bs[((nt*8 + kt)*64 + ln*4 + quad)*8];
        acc[nt] = __builtin_amdgcn_mfma_f32_16x16x32_bf16(afH[kt], bfr, acc[nt], 0, 0, 0);
        acc[nt] = __builtin_amdgcn_mfma_f32_16x16x32_bf16(afL[kt], bfr, acc[nt], 0, 0, 0);
      }

    // ---- lo weights: acc += Ahi@Blo ----
    __syncthreads();
    {
      const uint4* src = (const uint4*)(WAlo + (size_t)chunk * 32768);
      uint4* dst = (uint4*)bs;
      #pragma unroll
      for (int r = 0; r < 16; ++r) dst[r*256 + tid] = src[r*256 + tid];
    }
    __syncthreads();
    #pragma unroll
    for (int nt = 0; nt < 8; ++nt)
      #pragma unroll
      for (int kt = 0; kt < 8; ++kt) {
        const bf16x8 bfr = *(const bf16x8*)&bs[((nt*8 + kt)*64 + ln*4 + quad)*8];
        acc[nt] = __builtin_amdgcn_mfma_f32_16x16x32_bf16(afH[kt], bfr, acc[nt], 0, 0, 0);
      }

    // ---- epilogue: bias+relu, colmax, LDS bounce for coalesced stores ----
    __syncthreads();
    #pragma unroll
    for (int nt = 0; nt < 8; ++nt) {
      const float bv = ba[chunk*128 + nt*16 + ln];
      float m = 0.f;
      #pragma unroll
      for (int reg = 0; reg < 4; ++reg) {
        float h = acc[nt][reg] + bv;
        h = h > 0.f ? h : 0.f;
        bsf[(wave*16 + quad*4 + reg)*140 + nt*16 + ln] = h;
        m = fmaxf(m, h);
      }
      m = fmaxf(m, __shfl_xor(m, 16, 64));
      m = fmaxf(m, __shfl_xor(m, 32, 64));
      if (quad == 0) wsmax[wave][nt*16 + ln] = m;
    }
    __syncthreads();
    {
      const int row = tid >> 2, q4 = tid & 3;
      const float* rp = &bsf[row*140 + q4*32];
      bf16* gp = hats + (size_t)(row0 + row) * D + chunk*128 + q4*32;
      #pragma unroll
      for (int s = 0; s < 4; ++s) {
        float4 v0 = *(const float4*)&rp[s*8];
        float4 v1 = *(const float4*)&rp[s*8 + 4];
        float vv[8] = {v0.x, v0.y, v0.z, v0.w, v1.x, v1.y, v1.z, v1.w};
        bf16x8 pk;
        #pragma unroll
        for (int e = 0; e < 8; ++e) {
          bf16 b = __float2bfloat16(vv[e]);
          pk[e] = *(short*)&b;
        }
        *(bf16x8*)(gp + s*8) = pk;
      }
    }
    if (tid < 128) {
      float m = fmaxf(fmaxf(wsmax[0][tid], wsmax[1][tid]),
                      fmaxf(wsmax[2][tid], wsmax[3][tid]));
      atomicMax((unsigned int*)&HAts[(size_t)g*D + chunk*128 + tid],
                __float_as_uint(m));
    }
  }
}

// ---------------------------------------------------------------------------
// K-wconv: Wp1 rows 768..1023 (fp32) -> MFMA-tiled bf16 layout WBt.
// ---------------------------------------------------------------------------
__global__ void k_wconv(const float* __restrict__ Wp1, bf16* __restrict__ WBt) {
  int id = blockIdx.x * 256 + threadIdx.x;   // id = k*512 + n
  int k = id >> 9, n = id & 511;
  float v = Wp1[(size_t)(768 + k) * HID + n];
  int dst = (n >> 7) * 32768
          + (((((n >> 4) & 7) * 8 + (k >> 5)) * 16 + (n & 15)) * 4 + ((k >> 3) & 3)) * 8
          + (k & 7);
  WBt[dst] = __float2bfloat16(v);
}

// ---------------------------------------------------------------------------
// K2: build x0 (C=256, L=1534) transposed sequence
// ---------------------------------------------------------------------------
__global__ void k_build_x0(const float* __restrict__ nodes,
                           const float* __restrict__ HAts,
                           const bf16* __restrict__ hats,
                           const int* __restrict__ act,
                           float* __restrict__ x0) {
  int t = blockIdx.x * 256 + threadIdx.x;
  int c = blockIdx.y;
  if (t >= LSEQ) return;
  float v;
  if (t == LSEQ - 1) {
    v = nodes[(size_t)(G-1)*D + c];
  } else {
    int r = t / 3, m = t - 3*r;
    if (m == 0)      v = nodes[(size_t)r*D + c];
    else if (m == 1) v = HAts[(size_t)r*D + c];
    else             v = __bfloat162float(hats[(size_t)(r*PER + act[r])*D + c]);
  }
  x0[(size_t)c*LP + t] = v;
}

// ---------------------------------------------------------------------------
// K3: TCN conv partials, split-K over cin (blockIdx.z owns CPB chunks of 32).
// Block = 64t x 64ch, 256 threads, each thread 4t x 4ch. No atomics.
// ---------------------------------------------------------------------------
template<int DIL, int CPB, bool HASWD>
__global__ __launch_bounds__(256) void k_tcn4(
    const float* __restrict__ xin,
    const float* __restrict__ W,     // (Cout, Cin, 3)
    const float* __restrict__ Wd,    // (Cout, Cin) or unused
    float* __restrict__ ybuf,        // [NZ][Cout][LP]
    float* __restrict__ rbuf,        // [NZ][Cout][LP] (HASWD only)
    int Cin) {
  __shared__ __align__(16) float xs[32][80];                         // 10.0 KB
  __shared__ __align__(16) float wst[3][32][68];                     // 25.5 KB
  __shared__ __align__(16) float wds[HASWD ? 32 : 1][HASWD ? 68 : 4];

  const int tid = threadIdx.x;
  const int tt = tid & 15;
  const int cc = tid >> 4;
  const int t0 = blockIdx.x * 64;
  const int o0 = blockIdx.y * 64;
  const int Cout = gridDim.y << 6;

  float acc[4][4], res[4][4];
  #pragma unroll
  for (int it = 0; it < 4; ++it)
    #pragma unroll
    for (int ic = 0; ic < 4; ++ic) { acc[it][ic] = 0.f; res[it][ic] = 0.f; }

  for (int c = 0; c < CPB; ++c) {
    const int i0 = (blockIdx.z * CPB + c) * 32;
    __syncthreads();
    for (int idx = tid; idx < 32*20; idx += 256) {
      int r = idx / 20, j4 = idx - r*20;
      int tp = t0 - 16 + j4*4;
      float4 v;
      if (tp >= 0) v = *(const float4*)&xin[(size_t)(i0 + r)*LP + tp];
      else         v = make_float4(0.f, 0.f, 0.f, 0.f);
      *(float4*)&xs[r][j4*4] = v;
    }
    for (int idx = tid; idx < 64*32; idx += 256) {
      int o = idx >> 5, i = idx & 31;
      const float* wp = &W[((size_t)(o0 + o)*Cin + i0 + i)*3];
      wst[0][i][o] = wp[0];
      wst[1][i][o] = wp[1];
      wst[2][i][o] = wp[2];
      if constexpr (HASWD) wds[i][o] = Wd[(size_t)(o0 + o)*Cin + i0 + i];
    }
    __syncthreads();

    const int base = 16 + tt*4;
    #pragma unroll 2
    for (int i = 0; i < 32; ++i) {
      float4 xv0, xv1, xv2;
      if constexpr (DIL == 1) {
        float4 A = *(const float4*)&xs[i][base - 4];
        float4 B = *(const float4*)&xs[i][base];
        xv0 = make_float4(A.z, A.w, B.x, B.y);
        xv1 = make_float4(A.w, B.x, B.y, B.z);
        xv2 = B;
      } else if constexpr (DIL == 2) {
        float4 A = *(const float4*)&xs[i][base - 4];
        float4 B = *(const float4*)&xs[i][base];
        xv0 = A;
        xv1 = make_float4(A.z, A.w, B.x, B.y);
        xv2 = B;
      } else {
        xv0 = *(const float4*)&xs[i][base - 2*DIL];
        xv1 = *(const float4*)&xs[i][base - DIL];
        xv2 = *(const float4*)&xs[i][base];
      }
      float4 w0 = *(const float4*)&wst[0][i][cc*4];
      float4 w1 = *(const float4*)&wst[1][i][cc*4];
      float4 w2 = *(const float4*)&wst[2][i][cc*4];
      #pragma unroll
      for (int it = 0; it < 4; ++it) {
        float x0 = ((const float*)&xv0)[it];
        float x1 = ((const float*)&xv1)[it];
        float x2 = ((const float*)&xv2)[it];
        #pragma unroll
        for (int ic = 0; ic < 4; ++ic) {
          float a = acc[it][ic];
          a = fmaf(x0, ((const float*)&w0)[ic], a);
          a = fmaf(x1, ((const float*)&w1)[ic], a);
          a = fmaf(x2, ((const float*)&w2)[ic], a);
          acc[it][ic] = a;
        }
      }
      if constexpr (HASWD) {
        float4 wd4 = *(const float4*)&wds[i][cc*4];
        #pragma unroll
        for (int it = 0; it < 4; ++it) {
          float x2 = ((const float*)&xv2)[it];
          #pragma unroll
          for (int ic = 0; ic < 4; ++ic)
            res[it][ic] = fmaf(x2, ((const float*)&wd4)[ic], res[it][ic]);
        }
      }
    }
  }

  const int t = t0 + tt*4;
  #pragma unroll
  for (int ic = 0; ic < 4; ++ic) {
    const int ch = o0 + cc*4 + ic;
    const size_t off = ((size_t)blockIdx.z * Cout + ch) * LP + t;
    float4 v = make_float4(acc[0][ic], acc[1][ic], acc[2][ic], acc[3][ic]);
    *(float4*)&ybuf[off] = v;
    if constexpr (HASWD) {
      float4 rv = make_float4(res[0][ic], res[1][ic], res[2][ic], res[3][ic]);
      *(float4*)&rbuf[off] = rv;
    }
  }
}

// ---------------------------------------------------------------------------
// K3b: reduce NZ partial slices: out = relu(relu(sum_y+b) + res)
// ---------------------------------------------------------------------------
template<int NZ, bool HASWD>
__global__ __launch_bounds__(384) void k_tcn_red(
    const float* __restrict__ ybuf, const float* __restrict__ rbuf,
    const float* __restrict__ xin, const float* __restrict__ b,
    float* __restrict__ xout) {
  const int ch = blockIdx.x;
  const int Cout = gridDim.x;
  const int t = threadIdx.x * 4;
  const size_t stride = (size_t)Cout * LP;
  const size_t base = (size_t)ch * LP + t;

  float4 y = *(const float4*)&ybuf[base];
  #pragma unroll
  for (int z = 1; z < NZ; ++z) {
    float4 u = *(const float4*)&ybuf[base + z*stride];
    y.x += u.x; y.y += u.y; y.z += u.z; y.w += u.w;
  }
  const float bv = b[ch];
  y.x = fmaxf(y.x + bv, 0.f); y.y = fmaxf(y.y + bv, 0.f);
  y.z = fmaxf(y.z + bv, 0.f); y.w = fmaxf(y.w + bv, 0.f);

  float4 r;
  if constexpr (HASWD) {
    r = *(const float4*)&rbuf[base];
    #pragma unroll
    for (int z = 1; z < NZ; ++z) {
      float4 u = *(const float4*)&rbuf[base + z*stride];
      r.x += u.x; r.y += u.y; r.z += u.z; r.w += u.w;
    }
  } else {
    r = *(const float4*)&xin[base];
  }
  float4 v;
  v.x = fmaxf(y.x + r.x, 0.f); v.y = fmaxf(y.y + r.y, 0.f);
  v.z = fmaxf(y.z + r.z, 0.f); v.w = fmaxf(y.w + r.w, 0.f);
  *(float4*)&xout[base] = v;
}

// ---------------------------------------------------------------------------
// K4: Gterm[g][j] = bp1[j] + sum_{m<768} [query|hs|HAts][g][m] * Wp1[m][j]
// ---------------------------------------------------------------------------
__global__ __launch_bounds__(256) void k_gterm(
    const float* __restrict__ query, const float* __restrict__ HAts,
    const float* __restrict__ xfin,
    const float* __restrict__ Wp1, const float* __restrict__ bp1,
    float* __restrict__ Gterm) {
  __shared__ __align__(16) float s[8][768];
  const int tid = threadIdx.x;
  const int g0 = blockIdx.x * 8;
  for (int gg = 0; gg < 8; ++gg) {
    int g = g0 + gg;
    s[gg][tid]       = query[(size_t)g*D + tid];
    s[gg][256 + tid] = xfin[(size_t)tid*LP + 3*g];
    s[gg][512 + tid] = HAts[(size_t)g*D + tid];
  }
  __syncthreads();
  float acc[8][2];
  #pragma unroll
  for (int gg = 0; gg < 8; ++gg) { acc[gg][0] = 0.f; acc[gg][1] = 0.f; }
  for (int m4 = 0; m4 < 768/4; ++m4) {
    float4 sv[8];
    #pragma unroll
    for (int gg = 0; gg < 8; ++gg) sv[gg] = *(const float4*)&s[gg][m4*4];
    #pragma unroll
    for (int kk = 0; kk < 4; ++kk) {
      int m = m4*4 + kk;
      float w0 = Wp1[(size_t)m*HID + tid];
      float w1 = Wp1[(size_t)m*HID + tid + 256];
      #pragma unroll
      for (int gg = 0; gg < 8; ++gg) {
        float a = ((const float*)&sv[gg])[kk];
        acc[gg][0] = fmaf(a, w0, acc[gg][0]);
        acc[gg][1] = fmaf(a, w1, acc[gg][1]);
      }
    }
  }
  float b0 = bp1[tid], b1 = bp1[tid + 256];
  for (int gg = 0; gg < 8; ++gg) {
    Gterm[(size_t)(g0+gg)*HID + tid]       = acc[gg][0] + b0;
    Gterm[(size_t)(g0+gg)*HID + tid + 256] = acc[gg][1] + b1;
  }
}

// ---------------------------------------------------------------------------
// K5: MFMA. out[i] = relu(hats[i,:]@Wp1b + Gterm[g,:]) @ Wp2 + bp2
// ---------------------------------------------------------------------------
__global__ __launch_bounds__(256) void k_final_mfma(
    const bf16* __restrict__ hats, const bf16* __restrict__ WBt,
    const float* __restrict__ Gterm, const float* __restrict__ Wp2,
    const float* __restrict__ bp2, float* __restrict__ out) {
  __shared__ __align__(16) unsigned short bs[32768];  // 64 KB
  __shared__ float gs[512];
  __shared__ float w2s[512];

  const int tid = threadIdx.x;
  const int wave = tid >> 6, lane = tid & 63;
  const int ln = lane & 15, quad = lane >> 4;
  const int row0 = blockIdx.x * 64;
  const int g = row0 >> 7;

  gs[tid]        = Gterm[(size_t)g*HID + tid];
  gs[tid + 256]  = Gterm[(size_t)g*HID + tid + 256];
  w2s[tid]       = Wp2[tid];
  w2s[tid + 256] = Wp2[tid + 256];

  bf16x8 afrag[8];
  {
    const uint4* ap = (const uint4*)(hats + (size_t)(row0 + wave*16 + ln) * D);
    #pragma unroll
    for (int kt = 0; kt < 8; ++kt) {
      uint4 t = ap[kt*4 + quad];
      afrag[kt] = *(const bf16x8*)&t;
    }
  }

  float osum[4] = {0.f, 0.f, 0.f, 0.f};

  for (int chunk = 0; chunk < 4; ++chunk) {
    __syncthreads();
    const uint4* src = (const uint4*)(WBt + (size_t)chunk * 32768);
    uint4* dst = (uint4*)bs;
    #pragma unroll
    for (int r = 0; r < 16; ++r) dst[r*256 + tid] = src[r*256 + tid];
    __syncthreads();

    #pragma unroll
    for (int nt = 0; nt < 8; ++nt) {
      f32x4 acc = {0.f, 0.f, 0.f, 0.f};
      #pragma unroll
      for (int kt = 0; kt < 8; ++kt) {
        const bf16x8 bfr = *(const bf16x8*)&bs[((nt*8 + kt)*64 + ln*4 + quad)*8];
        acc = __builtin_amdgcn_mfma_f32_16x16x32_bf16(afrag[kt], bfr, acc, 0, 0, 0);
      }
      int n = chunk*128 + nt*16 + ln;
      float gv = gs[n], wv = w2s[n];
      #pragma unroll
      for (int reg = 0; reg < 4; ++reg) {
        float h = acc[reg] + gv;
        h = h > 0.f ? h : 0.f;
        osum[reg] = fmaf(h, wv, osum[reg]);
      }
    }
  }

  #pragma unroll
  for (int reg = 0; reg < 4; ++reg) {
    float v = osum[reg];
    v += __shfl_xor(v, 1, 64);
    v += __shfl_xor(v, 2, 64);
    v += __shfl_xor(v, 4, 64);
    v += __shfl_xor(v, 8, 64);
    osum[reg] = v;
  }
  if (ln == 0) {
    float b2 = bp2[0];
    #pragma unroll
    for (int reg = 0; reg < 4; ++reg)
      out[row0 + wave*16 + quad*4 + reg] = osum[reg] + b2;
  }
}

// ---------------------------------------------------------------------------
extern "C" void kernel_launch(void* const* d_in, const int* in_sizes, int n_in,
                              void* d_out, int out_size, void* d_ws, size_t ws_size,
                              hipStream_t stream) {
  (void)in_sizes; (void)n_in; (void)out_size; (void)ws_size;
  const float* NEs   = (const float*)d_in[0];
  const float* nodes = (const float*)d_in[1];
  const float* query = (const float*)d_in[2];
  const int*   act   = (const int*)d_in[4];
  const float* Wa    = (const float*)d_in[5];
  const float* ba    = (const float*)d_in[6];
  const float* Wc0   = (const float*)d_in[7];
  const float* bc0   = (const float*)d_in[8];
  const float* Wc1   = (const float*)d_in[9];
  const float* bc1   = (const float*)d_in[10];
  const float* Wd1   = (const float*)d_in[11];
  const float* Wc2   = (const float*)d_in[12];
  const float* bc2   = (const float*)d_in[13];
  const float* Wc3   = (const float*)d_in[14];
  const float* bc3   = (const float*)d_in[15];
  const float* Wd3   = (const float*)d_in[16];
  const float* Wp1   = (const float*)d_in[17];
  const float* bp1   = (const float*)d_in[18];
  const float* Wp2   = (const float*)d_in[19];
  const float* bp2   = (const float*)d_in[20];
  float* out = (float*)d_out;

  char* ws = (char*)d_ws;
  bf16*  hats  = (bf16*)ws;  ws += (size_t)NROW * D * sizeof(bf16);
  float* HAts  = (float*)ws; ws += (size_t)G * D * sizeof(float);
  float* xa    = (float*)ws; ws += (size_t)512 * LP * sizeof(float);
  float* xb    = (float*)ws; ws += (size_t)512 * LP * sizeof(float);
  float* Gterm = (float*)ws; ws += (size_t)G * HID * sizeof(float);
  bf16*  WBt   = (bf16*)ws;  ws += (size_t)D * HID * sizeof(bf16);
  bf16*  WAhi  = (bf16*)ws;  ws += (size_t)D * D * sizeof(bf16);
  bf16*  WAlo  = (bf16*)ws;  ws += (size_t)D * D * sizeof(bf16);
  // split-K partial buffers: up to 2048 rows x LP each (12.6 MB each)
  float* P0 = (float*)ws; ws += (size_t)2048 * LP * sizeof(float);
  float* P1 = (float*)ws; ws += (size_t)2048 * LP * sizeof(float);

  k_zeroH<<<G*D/1024, 256, 0, stream>>>((float4*)HAts);
  k_waprep<<<256, 256, 0, stream>>>(Wa, WAhi, WAlo);
  k_hats_mfma<<<NROW/64, 256, 0, stream>>>(NEs, WAhi, WAlo, ba, hats, HAts);
  k_wconv<<<512, 256, 0, stream>>>(Wp1, WBt);
  k_build_x0<<<dim3(6, 256), 256, 0, stream>>>(nodes, HAts, hats, act, xa);

  // L0: 256->256, dil=1, NZ=8 (CPB=1): 768 blocks
  k_tcn4<1, 1, false><<<dim3(24, 4, 8), 256, 0, stream>>>(xa, Wc0, nullptr, P0, nullptr, 256);
  k_tcn_red<8, false><<<256, 384, 0, stream>>>(P0, nullptr, xa, bc0, xb);
  // L1: 256->512, dil=2, Wd, NZ=4 (CPB=2): 768 blocks
  k_tcn4<2, 2, true ><<<dim3(24, 8, 4), 256, 0, stream>>>(xb, Wc1, Wd1, P0, P1, 256);
  k_tcn_red<4, true ><<<512, 384, 0, stream>>>(P0, P1, xb, bc1, xa);
  // L2: 512->512, dil=4, NZ=4 (CPB=4): 768 blocks
  k_tcn4<4, 4, false><<<dim3(24, 8, 4), 256, 0, stream>>>(xa, Wc2, nullptr, P0, nullptr, 512);
  k_tcn_red<4, false><<<512, 384, 0, stream>>>(P0, nullptr, xa, bc2, xb);
  // L3: 512->256, dil=8, Wd, NZ=8 (CPB=2): 768 blocks
  k_tcn4<8, 2, true ><<<dim3(24, 4, 8), 256, 0, stream>>>(xb, Wc3, Wd3, P0, P1, 512);
  k_tcn_red<8, true ><<<256, 384, 0, stream>>>(P0, P1, xb, bc3, xa);

  k_gterm<<<G/8, 256, 0, stream>>>(query, HAts, xa, Wp1, bp1, Gterm);
  k_final_mfma<<<NROW/64, 256, 0, stream>>>(hats, WBt, Gterm, Wp2, bp2, out);
}

// Round 4
// 372.896 us; speedup vs baseline: 2.6435x; 1.1808x over previous
//
#include <hip/hip_runtime.h>
#include <hip/hip_bf16.h>

#define D 256
#define G 512
#define PER 128
#define NROW (G*PER)   // 65536
#define LSEQ 1534
#define LP 1536
#define HID 512

typedef __hip_bfloat16 bf16;
typedef __attribute__((ext_vector_type(8))) short bf16x8;
typedef __attribute__((ext_vector_type(4))) float f32x4;

// ---------------------------------------------------------------------------
// K-zeroH: zero HAts (needed for uint atomicMax accumulation)
// ---------------------------------------------------------------------------
__global__ __launch_bounds__(256) void k_zeroH(float4* __restrict__ p) {
  p[blockIdx.x * 256 + threadIdx.x] = make_float4(0.f, 0.f, 0.f, 0.f);
}

// ---------------------------------------------------------------------------
// K-waprep: Wa (256x256 fp32, [k][n]) -> MFMA-tiled bf16 hi/lo buffers.
// ---------------------------------------------------------------------------
__global__ void k_waprep(const float* __restrict__ Wa,
                         bf16* __restrict__ WAhi, bf16* __restrict__ WAlo) {
  int id = blockIdx.x * 256 + threadIdx.x;   // id = k*256 + n
  int k = id >> 8, n = id & 255;
  float v = Wa[(size_t)k * D + n];
  bf16 h = __float2bfloat16(v);
  float hf = __bfloat162float(h);
  bf16 l = __float2bfloat16(v - hf);
  int dst = (n >> 7) * 32768
          + (((((n >> 4) & 7) * 8 + (k >> 5)) * 16 + (n & 15)) * 4 + ((k >> 3) & 3)) * 8
          + (k & 7);
  WAhi[dst] = h;
  WAlo[dst] = l;
}

// ---------------------------------------------------------------------------
// K1: hats = relu(NEs @ Wa + ba) via split-bf16 MFMA (AhiBhi+AloBhi+AhiBlo).
// ---------------------------------------------------------------------------
__global__ __launch_bounds__(256) void k_hats_mfma(
    const float* __restrict__ NEs, const bf16* __restrict__ WAhi,
    const bf16* __restrict__ WAlo, const float* __restrict__ ba,
    bf16* __restrict__ hats, float* __restrict__ HAts) {
  __shared__ __align__(16) unsigned short bs[32768];  // 64 KB (reused as bounce)
  __shared__ float wsmax[4][128];

  const int tid = threadIdx.x;
  const int wave = tid >> 6, lane = tid & 63;
  const int ln = lane & 15, quad = lane >> 4;
  const int row0 = blockIdx.x * 64;
  const int g = row0 >> 7;

  bf16x8 afH[8], afL[8];
  {
    const float4* ap = (const float4*)(NEs + (size_t)(row0 + wave*16 + ln) * D);
    #pragma unroll
    for (int kt = 0; kt < 8; ++kt) {
      float4 x0 = ap[kt*8 + quad*2];
      float4 x1 = ap[kt*8 + quad*2 + 1];
      float xv[8] = {x0.x, x0.y, x0.z, x0.w, x1.x, x1.y, x1.z, x1.w};
      bf16x8 hv, lv;
      #pragma unroll
      for (int e = 0; e < 8; ++e) {
        bf16 h = __float2bfloat16(xv[e]);
        bf16 l = __float2bfloat16(xv[e] - __bfloat162float(h));
        hv[e] = *(short*)&h;
        lv[e] = *(short*)&l;
      }
      afH[kt] = hv;
      afL[kt] = lv;
    }
  }

  float* bsf = (float*)bs;   // bounce view: [64][140] floats (35 KB)

  for (int chunk = 0; chunk < 2; ++chunk) {
    f32x4 acc[8];
    #pragma unroll
    for (int nt = 0; nt < 8; ++nt) acc[nt] = (f32x4){0.f, 0.f, 0.f, 0.f};

    __syncthreads();
    {
      const uint4* src = (const uint4*)(WAhi + (size_t)chunk * 32768);
      uint4* dst = (uint4*)bs;
      #pragma unroll
      for (int r = 0; r < 16; ++r) dst[r*256 + tid] = src[r*256 + tid];
    }
    __syncthreads();
    #pragma unroll
    for (int nt = 0; nt < 8; ++nt)
      #pragma unroll
      for (int kt = 0; kt < 8; ++kt) {
        const bf16x8 bfr = *(const bf16x8*)&bs[((nt*8 + kt)*64 + ln*4 + quad)*8];
        acc[nt] = __builtin_amdgcn_mfma_f32_16x16x32_bf16(afH[kt], bfr, acc[nt], 0, 0, 0);
        acc[nt] = __builtin_amdgcn_mfma_f32_16x16x32_bf16(afL[kt], bfr, acc[nt], 0, 0, 0);
      }

    __syncthreads();
    {
      const uint4* src = (const uint4*)(WAlo + (size_t)chunk * 32768);
      uint4* dst = (uint4*)bs;
      #pragma unroll
      for (int r = 0; r < 16; ++r) dst[r*256 + tid] = src[r*256 + tid];
    }
    __syncthreads();
    #pragma unroll
    for (int nt = 0; nt < 8; ++nt)
      #pragma unroll
      for (int kt = 0; kt < 8; ++kt) {
        const bf16x8 bfr = *(const bf16x8*)&bs[((nt*8 + kt)*64 + ln*4 + quad)*8];
        acc[nt] = __builtin_amdgcn_mfma_f32_16x16x32_bf16(afH[kt], bfr, acc[nt], 0, 0, 0);
      }

    __syncthreads();
    #pragma unroll
    for (int nt = 0; nt < 8; ++nt) {
      const float bv = ba[chunk*128 + nt*16 + ln];
      float m = 0.f;
      #pragma unroll
      for (int reg = 0; reg < 4; ++reg) {
        float h = acc[nt][reg] + bv;
        h = h > 0.f ? h : 0.f;
        bsf[(wave*16 + quad*4 + reg)*140 + nt*16 + ln] = h;
        m = fmaxf(m, h);
      }
      m = fmaxf(m, __shfl_xor(m, 16, 64));
      m = fmaxf(m, __shfl_xor(m, 32, 64));
      if (quad == 0) wsmax[wave][nt*16 + ln] = m;
    }
    __syncthreads();
    {
      const int row = tid >> 2, q4 = tid & 3;
      const float* rp = &bsf[row*140 + q4*32];
      bf16* gp = hats + (size_t)(row0 + row) * D + chunk*128 + q4*32;
      #pragma unroll
      for (int s = 0; s < 4; ++s) {
        float4 v0 = *(const float4*)&rp[s*8];
        float4 v1 = *(const float4*)&rp[s*8 + 4];
        float vv[8] = {v0.x, v0.y, v0.z, v0.w, v1.x, v1.y, v1.z, v1.w};
        bf16x8 pk;
        #pragma unroll
        for (int e = 0; e < 8; ++e) {
          bf16 b = __float2bfloat16(vv[e]);
          pk[e] = *(short*)&b;
        }
        *(bf16x8*)(gp + s*8) = pk;
      }
    }
    if (tid < 128) {
      float m = fmaxf(fmaxf(wsmax[0][tid], wsmax[1][tid]),
                      fmaxf(wsmax[2][tid], wsmax[3][tid]));
      atomicMax((unsigned int*)&HAts[(size_t)g*D + chunk*128 + tid],
                __float_as_uint(m));
    }
  }
}

// ---------------------------------------------------------------------------
// K-wconv: Wp1 rows 768..1023 (fp32) -> MFMA-tiled bf16 layout WBt.
// ---------------------------------------------------------------------------
__global__ void k_wconv(const float* __restrict__ Wp1, bf16* __restrict__ WBt) {
  int id = blockIdx.x * 256 + threadIdx.x;   // id = k*512 + n
  int k = id >> 9, n = id & 511;
  float v = Wp1[(size_t)(768 + k) * HID + n];
  int dst = (n >> 7) * 32768
          + (((((n >> 4) & 7) * 8 + (k >> 5)) * 16 + (n & 15)) * 4 + ((k >> 3) & 3)) * 8
          + (k & 7);
  WBt[dst] = __float2bfloat16(v);
}

// ---------------------------------------------------------------------------
// K-wp1prep: Wp1 rows 0..767 -> MFMA-tiled bf16 hi/lo. Tiles of
// (k-chunk 256) x (n-chunk 128), tile index = nc*3 + kc, 32768 elems each.
// ---------------------------------------------------------------------------
__global__ void k_wp1prep(const float* __restrict__ Wp1,
                          bf16* __restrict__ Bhi, bf16* __restrict__ Blo) {
  int id = blockIdx.x * 256 + threadIdx.x;   // id = k*512 + n, k<768
  int k = id >> 9, n = id & 511;
  float v = Wp1[(size_t)k * HID + n];
  bf16 h = __float2bfloat16(v);
  bf16 l = __float2bfloat16(v - __bfloat162float(h));
  int kc = k >> 8, kr = k & 255;
  int nc = n >> 7, nr = n & 127;
  int dst = (nc*3 + kc) * 32768
          + ((((nr >> 4) * 8 + (kr >> 5)) * 16 + (nr & 15)) * 4 + ((kr >> 3) & 3)) * 8
          + (kr & 7);
  Bhi[dst] = h;
  Blo[dst] = l;
}

// ---------------------------------------------------------------------------
// K-sprep: S = [query | hs | HAts] (512 x 768) -> row-major bf16 hi/lo
// ---------------------------------------------------------------------------
__global__ void k_sprep(const float* __restrict__ query,
                        const float* __restrict__ HAts,
                        const float* __restrict__ xfin,
                        bf16* __restrict__ Shi, bf16* __restrict__ Slo) {
  int m = blockIdx.x * 256 + threadIdx.x;   // 0..767
  int g = blockIdx.y;
  float v;
  if (m < 256)      v = query[(size_t)g*D + m];
  else if (m < 512) v = xfin[(size_t)(m - 256)*LP + 3*g];
  else              v = HAts[(size_t)g*D + (m - 512)];
  bf16 h = __float2bfloat16(v);
  bf16 l = __float2bfloat16(v - __bfloat162float(h));
  Shi[(size_t)g*768 + m] = h;
  Slo[(size_t)g*768 + m] = l;
}

// ---------------------------------------------------------------------------
// K4: Gterm = S @ Wp1[0:768] + bp1 via split-bf16 MFMA.
// grid = (4 n-chunks, 8 g-tiles of 64). Loop 3 k-chunks, staging hi then lo B.
// ---------------------------------------------------------------------------
__global__ __launch_bounds__(256) void k_gterm_mfma(
    const bf16* __restrict__ Shi, const bf16* __restrict__ Slo,
    const bf16* __restrict__ WB1hi, const bf16* __restrict__ WB1lo,
    const float* __restrict__ bp1, float* __restrict__ Gterm) {
  __shared__ __align__(16) unsigned short bs[32768];  // 64 KB

  const int tid = threadIdx.x;
  const int wave = tid >> 6, lane = tid & 63;
  const int ln = lane & 15, quad = lane >> 4;
  const int nc = blockIdx.x;
  const int row0 = blockIdx.y * 64;

  f32x4 acc[8];
  #pragma unroll
  for (int nt = 0; nt < 8; ++nt) acc[nt] = (f32x4){0.f, 0.f, 0.f, 0.f};

  const uint4* ahp = (const uint4*)(Shi + (size_t)(row0 + wave*16 + ln) * 768);
  const uint4* alp = (const uint4*)(Slo + (size_t)(row0 + wave*16 + ln) * 768);

  for (int kc = 0; kc < 3; ++kc) {
    bf16x8 afH[8], afL[8];
    #pragma unroll
    for (int kt = 0; kt < 8; ++kt) {
      uint4 th = ahp[kc*32 + kt*4 + quad];
      uint4 tl = alp[kc*32 + kt*4 + quad];
      afH[kt] = *(const bf16x8*)&th;
      afL[kt] = *(const bf16x8*)&tl;
    }

    __syncthreads();
    {
      const uint4* src = (const uint4*)(WB1hi + (size_t)(nc*3 + kc) * 32768);
      uint4* dst = (uint4*)bs;
      #pragma unroll
      for (int r = 0; r < 16; ++r) dst[r*256 + tid] = src[r*256 + tid];
    }
    __syncthreads();
    #pragma unroll
    for (int nt = 0; nt < 8; ++nt)
      #pragma unroll
      for (int kt = 0; kt < 8; ++kt) {
        const bf16x8 bfr = *(const bf16x8*)&bs[((nt*8 + kt)*64 + ln*4 + quad)*8];
        acc[nt] = __builtin_amdgcn_mfma_f32_16x16x32_bf16(afH[kt], bfr, acc[nt], 0, 0, 0);
        acc[nt] = __builtin_amdgcn_mfma_f32_16x16x32_bf16(afL[kt], bfr, acc[nt], 0, 0, 0);
      }

    __syncthreads();
    {
      const uint4* src = (const uint4*)(WB1lo + (size_t)(nc*3 + kc) * 32768);
      uint4* dst = (uint4*)bs;
      #pragma unroll
      for (int r = 0; r < 16; ++r) dst[r*256 + tid] = src[r*256 + tid];
    }
    __syncthreads();
    #pragma unroll
    for (int nt = 0; nt < 8; ++nt)
      #pragma unroll
      for (int kt = 0; kt < 8; ++kt) {
        const bf16x8 bfr = *(const bf16x8*)&bs[((nt*8 + kt)*64 + ln*4 + quad)*8];
        acc[nt] = __builtin_amdgcn_mfma_f32_16x16x32_bf16(afH[kt], bfr, acc[nt], 0, 0, 0);
      }
  }

  #pragma unroll
  for (int nt = 0; nt < 8; ++nt) {
    const int col = nc*128 + nt*16 + ln;
    const float bv = bp1[col];
    #pragma unroll
    for (int reg = 0; reg < 4; ++reg)
      Gterm[(size_t)(row0 + wave*16 + quad*4 + reg) * HID + col] = acc[nt][reg] + bv;
  }
}

// ---------------------------------------------------------------------------
// K2: build x0 (C=256, L=1534) transposed sequence
// ---------------------------------------------------------------------------
__global__ void k_build_x0(const float* __restrict__ nodes,
                           const float* __restrict__ HAts,
                           const bf16* __restrict__ hats,
                           const int* __restrict__ act,
                           float* __restrict__ x0) {
  int t = blockIdx.x * 256 + threadIdx.x;
  int c = blockIdx.y;
  if (t >= LSEQ) return;
  float v;
  if (t == LSEQ - 1) {
    v = nodes[(size_t)(G-1)*D + c];
  } else {
    int r = t / 3, m = t - 3*r;
    if (m == 0)      v = nodes[(size_t)r*D + c];
    else if (m == 1) v = HAts[(size_t)r*D + c];
    else             v = __bfloat162float(hats[(size_t)(r*PER + act[r])*D + c]);
  }
  x0[(size_t)c*LP + t] = v;
}

// ---------------------------------------------------------------------------
// K3: TCN conv partials, split-K over cin (blockIdx.z owns CPB chunks of 32).
// ---------------------------------------------------------------------------
template<int DIL, int CPB, bool HASWD>
__global__ __launch_bounds__(256) void k_tcn4(
    const float* __restrict__ xin,
    const float* __restrict__ W,     // (Cout, Cin, 3)
    const float* __restrict__ Wd,    // (Cout, Cin) or unused
    float* __restrict__ ybuf,        // [NZ][Cout][LP]
    float* __restrict__ rbuf,        // [NZ][Cout][LP] (HASWD only)
    int Cin) {
  __shared__ __align__(16) float xs[32][80];
  __shared__ __align__(16) float wst[3][32][68];
  __shared__ __align__(16) float wds[HASWD ? 32 : 1][HASWD ? 68 : 4];

  const int tid = threadIdx.x;
  const int tt = tid & 15;
  const int cc = tid >> 4;
  const int t0 = blockIdx.x * 64;
  const int o0 = blockIdx.y * 64;
  const int Cout = gridDim.y << 6;

  float acc[4][4], res[4][4];
  #pragma unroll
  for (int it = 0; it < 4; ++it)
    #pragma unroll
    for (int ic = 0; ic < 4; ++ic) { acc[it][ic] = 0.f; res[it][ic] = 0.f; }

  for (int c = 0; c < CPB; ++c) {
    const int i0 = (blockIdx.z * CPB + c) * 32;
    __syncthreads();
    for (int idx = tid; idx < 32*20; idx += 256) {
      int r = idx / 20, j4 = idx - r*20;
      int tp = t0 - 16 + j4*4;
      float4 v;
      if (tp >= 0) v = *(const float4*)&xin[(size_t)(i0 + r)*LP + tp];
      else         v = make_float4(0.f, 0.f, 0.f, 0.f);
      *(float4*)&xs[r][j4*4] = v;
    }
    for (int idx = tid; idx < 64*32; idx += 256) {
      int o = idx >> 5, i = idx & 31;
      const float* wp = &W[((size_t)(o0 + o)*Cin + i0 + i)*3];
      wst[0][i][o] = wp[0];
      wst[1][i][o] = wp[1];
      wst[2][i][o] = wp[2];
      if constexpr (HASWD) wds[i][o] = Wd[(size_t)(o0 + o)*Cin + i0 + i];
    }
    __syncthreads();

    const int base = 16 + tt*4;
    #pragma unroll 2
    for (int i = 0; i < 32; ++i) {
      float4 xv0, xv1, xv2;
      if constexpr (DIL == 1) {
        float4 A = *(const float4*)&xs[i][base - 4];
        float4 B = *(const float4*)&xs[i][base];
        xv0 = make_float4(A.z, A.w, B.x, B.y);
        xv1 = make_float4(A.w, B.x, B.y, B.z);
        xv2 = B;
      } else if constexpr (DIL == 2) {
        float4 A = *(const float4*)&xs[i][base - 4];
        float4 B = *(const float4*)&xs[i][base];
        xv0 = A;
        xv1 = make_float4(A.z, A.w, B.x, B.y);
        xv2 = B;
      } else {
        xv0 = *(const float4*)&xs[i][base - 2*DIL];
        xv1 = *(const float4*)&xs[i][base - DIL];
        xv2 = *(const float4*)&xs[i][base];
      }
      float4 w0 = *(const float4*)&wst[0][i][cc*4];
      float4 w1 = *(const float4*)&wst[1][i][cc*4];
      float4 w2 = *(const float4*)&wst[2][i][cc*4];
      #pragma unroll
      for (int it = 0; it < 4; ++it) {
        float x0 = ((const float*)&xv0)[it];
        float x1 = ((const float*)&xv1)[it];
        float x2 = ((const float*)&xv2)[it];
        #pragma unroll
        for (int ic = 0; ic < 4; ++ic) {
          float a = acc[it][ic];
          a = fmaf(x0, ((const float*)&w0)[ic], a);
          a = fmaf(x1, ((const float*)&w1)[ic], a);
          a = fmaf(x2, ((const float*)&w2)[ic], a);
          acc[it][ic] = a;
        }
      }
      if constexpr (HASWD) {
        float4 wd4 = *(const float4*)&wds[i][cc*4];
        #pragma unroll
        for (int it = 0; it < 4; ++it) {
          float x2 = ((const float*)&xv2)[it];
          #pragma unroll
          for (int ic = 0; ic < 4; ++ic)
            res[it][ic] = fmaf(x2, ((const float*)&wd4)[ic], res[it][ic]);
        }
      }
    }
  }

  const int t = t0 + tt*4;
  #pragma unroll
  for (int ic = 0; ic < 4; ++ic) {
    const int ch = o0 + cc*4 + ic;
    const size_t off = ((size_t)blockIdx.z * Cout + ch) * LP + t;
    float4 v = make_float4(acc[0][ic], acc[1][ic], acc[2][ic], acc[3][ic]);
    *(float4*)&ybuf[off] = v;
    if constexpr (HASWD) {
      float4 rv = make_float4(res[0][ic], res[1][ic], res[2][ic], res[3][ic]);
      *(float4*)&rbuf[off] = rv;
    }
  }
}

// ---------------------------------------------------------------------------
// K3b: reduce NZ partial slices: out = relu(relu(sum_y+b) + res)
// ---------------------------------------------------------------------------
template<int NZ, bool HASWD>
__global__ __launch_bounds__(384) void k_tcn_red(
    const float* __restrict__ ybuf, const float* __restrict__ rbuf,
    const float* __restrict__ xin, const float* __restrict__ b,
    float* __restrict__ xout) {
  const int ch = blockIdx.x;
  const int Cout = gridDim.x;
  const int t = threadIdx.x * 4;
  const size_t stride = (size_t)Cout * LP;
  const size_t base = (size_t)ch * LP + t;

  float4 y = *(const float4*)&ybuf[base];
  #pragma unroll
  for (int z = 1; z < NZ; ++z) {
    float4 u = *(const float4*)&ybuf[base + z*stride];
    y.x += u.x; y.y += u.y; y.z += u.z; y.w += u.w;
  }
  const float bv = b[ch];
  y.x = fmaxf(y.x + bv, 0.f); y.y = fmaxf(y.y + bv, 0.f);
  y.z = fmaxf(y.z + bv, 0.f); y.w = fmaxf(y.w + bv, 0.f);

  float4 r;
  if constexpr (HASWD) {
    r = *(const float4*)&rbuf[base];
    #pragma unroll
    for (int z = 1; z < NZ; ++z) {
      float4 u = *(const float4*)&rbuf[base + z*stride];
      r.x += u.x; r.y += u.y; r.z += u.z; r.w += u.w;
    }
  } else {
    r = *(const float4*)&xin[base];
  }
  float4 v;
  v.x = fmaxf(y.x + r.x, 0.f); v.y = fmaxf(y.y + r.y, 0.f);
  v.z = fmaxf(y.z + r.z, 0.f); v.w = fmaxf(y.w + r.w, 0.f);
  *(float4*)&xout[base] = v;
}

// ---------------------------------------------------------------------------
// K5: MFMA. out[i] = relu(hats[i,:]@Wp1b + Gterm[g,:]) @ Wp2 + bp2
// ---------------------------------------------------------------------------
__global__ __launch_bounds__(256) void k_final_mfma(
    const bf16* __restrict__ hats, const bf16* __restrict__ WBt,
    const float* __restrict__ Gterm, const float* __restrict__ Wp2,
    const float* __restrict__ bp2, float* __restrict__ out) {
  __shared__ __align__(16) unsigned short bs[32768];  // 64 KB
  __shared__ float gs[512];
  __shared__ float w2s[512];

  const int tid = threadIdx.x;
  const int wave = tid >> 6, lane = tid & 63;
  const int ln = lane & 15, quad = lane >> 4;
  const int row0 = blockIdx.x * 64;
  const int g = row0 >> 7;

  gs[tid]        = Gterm[(size_t)g*HID + tid];
  gs[tid + 256]  = Gterm[(size_t)g*HID + tid + 256];
  w2s[tid]       = Wp2[tid];
  w2s[tid + 256] = Wp2[tid + 256];

  bf16x8 afrag[8];
  {
    const uint4* ap = (const uint4*)(hats + (size_t)(row0 + wave*16 + ln) * D);
    #pragma unroll
    for (int kt = 0; kt < 8; ++kt) {
      uint4 t = ap[kt*4 + quad];
      afrag[kt] = *(const bf16x8*)&t;
    }
  }

  float osum[4] = {0.f, 0.f, 0.f, 0.f};

  for (int chunk = 0; chunk < 4; ++chunk) {
    __syncthreads();
    const uint4* src = (const uint4*)(WBt + (size_t)chunk * 32768);
    uint4* dst = (uint4*)bs;
    #pragma unroll
    for (int r = 0; r < 16; ++r) dst[r*256 + tid] = src[r*256 + tid];
    __syncthreads();

    #pragma unroll
    for (int nt = 0; nt < 8; ++nt) {
      f32x4 acc = {0.f, 0.f, 0.f, 0.f};
      #pragma unroll
      for (int kt = 0; kt < 8; ++kt) {
        const bf16x8 bfr = *(const bf16x8*)&bs[((nt*8 + kt)*64 + ln*4 + quad)*8];
        acc = __builtin_amdgcn_mfma_f32_16x16x32_bf16(afrag[kt], bfr, acc, 0, 0, 0);
      }
      int n = chunk*128 + nt*16 + ln;
      float gv = gs[n], wv = w2s[n];
      #pragma unroll
      for (int reg = 0; reg < 4; ++reg) {
        float h = acc[reg] + gv;
        h = h > 0.f ? h : 0.f;
        osum[reg] = fmaf(h, wv, osum[reg]);
      }
    }
  }

  #pragma unroll
  for (int reg = 0; reg < 4; ++reg) {
    float v = osum[reg];
    v += __shfl_xor(v, 1, 64);
    v += __shfl_xor(v, 2, 64);
    v += __shfl_xor(v, 4, 64);
    v += __shfl_xor(v, 8, 64);
    osum[reg] = v;
  }
  if (ln == 0) {
    float b2 = bp2[0];
    #pragma unroll
    for (int reg = 0; reg < 4; ++reg)
      out[row0 + wave*16 + quad*4 + reg] = osum[reg] + b2;
  }
}

// ---------------------------------------------------------------------------
extern "C" void kernel_launch(void* const* d_in, const int* in_sizes, int n_in,
                              void* d_out, int out_size, void* d_ws, size_t ws_size,
                              hipStream_t stream) {
  (void)in_sizes; (void)n_in; (void)out_size; (void)ws_size;
  const float* NEs   = (const float*)d_in[0];
  const float* nodes = (const float*)d_in[1];
  const float* query = (const float*)d_in[2];
  const int*   act   = (const int*)d_in[4];
  const float* Wa    = (const float*)d_in[5];
  const float* ba    = (const float*)d_in[6];
  const float* Wc0   = (const float*)d_in[7];
  const float* bc0   = (const float*)d_in[8];
  const float* Wc1   = (const float*)d_in[9];
  const float* bc1   = (const float*)d_in[10];
  const float* Wd1   = (const float*)d_in[11];
  const float* Wc2   = (const float*)d_in[12];
  const float* bc2   = (const float*)d_in[13];
  const float* Wc3   = (const float*)d_in[14];
  const float* bc3   = (const float*)d_in[15];
  const float* Wd3   = (const float*)d_in[16];
  const float* Wp1   = (const float*)d_in[17];
  const float* bp1   = (const float*)d_in[18];
  const float* Wp2   = (const float*)d_in[19];
  const float* bp2   = (const float*)d_in[20];
  float* out = (float*)d_out;

  char* ws = (char*)d_ws;
  bf16*  hats  = (bf16*)ws;  ws += (size_t)NROW * D * sizeof(bf16);
  float* HAts  = (float*)ws; ws += (size_t)G * D * sizeof(float);
  float* xa    = (float*)ws; ws += (size_t)512 * LP * sizeof(float);
  float* xb    = (float*)ws; ws += (size_t)512 * LP * sizeof(float);
  float* Gterm = (float*)ws; ws += (size_t)G * HID * sizeof(float);
  bf16*  WBt   = (bf16*)ws;  ws += (size_t)D * HID * sizeof(bf16);
  bf16*  WAhi  = (bf16*)ws;  ws += (size_t)D * D * sizeof(bf16);
  bf16*  WAlo  = (bf16*)ws;  ws += (size_t)D * D * sizeof(bf16);
  bf16*  WB1hi = (bf16*)ws;  ws += (size_t)768 * HID * sizeof(bf16);
  bf16*  WB1lo = (bf16*)ws;  ws += (size_t)768 * HID * sizeof(bf16);
  bf16*  Shi   = (bf16*)ws;  ws += (size_t)G * 768 * sizeof(bf16);
  bf16*  Slo   = (bf16*)ws;  ws += (size_t)G * 768 * sizeof(bf16);
  // split-K partial buffers: up to 2048 rows x LP each (12.6 MB each)
  float* P0 = (float*)ws; ws += (size_t)2048 * LP * sizeof(float);
  float* P1 = (float*)ws; ws += (size_t)2048 * LP * sizeof(float);

  k_zeroH<<<G*D/1024, 256, 0, stream>>>((float4*)HAts);
  k_waprep<<<256, 256, 0, stream>>>(Wa, WAhi, WAlo);
  k_hats_mfma<<<NROW/64, 256, 0, stream>>>(NEs, WAhi, WAlo, ba, hats, HAts);
  k_wconv<<<512, 256, 0, stream>>>(Wp1, WBt);
  k_wp1prep<<<1536, 256, 0, stream>>>(Wp1, WB1hi, WB1lo);
  k_build_x0<<<dim3(6, 256), 256, 0, stream>>>(nodes, HAts, hats, act, xa);

  // L0: 256->256, dil=1, NZ=8 (CPB=1): 768 blocks
  k_tcn4<1, 1, false><<<dim3(24, 4, 8), 256, 0, stream>>>(xa, Wc0, nullptr, P0, nullptr, 256);
  k_tcn_red<8, false><<<256, 384, 0, stream>>>(P0, nullptr, xa, bc0, xb);
  // L1: 256->512, dil=2, Wd, NZ=4 (CPB=2): 768 blocks
  k_tcn4<2, 2, true ><<<dim3(24, 8, 4), 256, 0, stream>>>(xb, Wc1, Wd1, P0, P1, 256);
  k_tcn_red<4, true ><<<512, 384, 0, stream>>>(P0, P1, xb, bc1, xa);
  // L2: 512->512, dil=4, NZ=4 (CPB=4): 768 blocks
  k_tcn4<4, 4, false><<<dim3(24, 8, 4), 256, 0, stream>>>(xa, Wc2, nullptr, P0, nullptr, 512);
  k_tcn_red<4, false><<<512, 384, 0, stream>>>(P0, nullptr, xa, bc2, xb);
  // L3: 512->256, dil=8, Wd, NZ=8 (CPB=2): 768 blocks
  k_tcn4<8, 2, true ><<<dim3(24, 4, 8), 256, 0, stream>>>(xb, Wc3, Wd3, P0, P1, 512);
  k_tcn_red<8, true ><<<256, 384, 0, stream>>>(P0, P1, xb, bc3, xa);

  k_sprep<<<dim3(3, G), 256, 0, stream>>>(query, HAts, xa, Shi, Slo);
  k_gterm_mfma<<<dim3(4, 8), 256, 0, stream>>>(Shi, Slo, WB1hi, WB1lo, bp1, Gterm);
  k_final_mfma<<<NROW/64, 256, 0, stream>>>(hats, WBt, Gterm, Wp2, bp2, out);
}